// Round 12
// baseline (112.672 us; speedup 1.0000x reference)
//
#include <hip/hip_runtime.h>
#include <hip/hip_bf16.h>
#include <hip/hip_fp16.h>

#define NN   8
#define CIN  128
#define HH   96
#define WW   96
#define COUT 256
#define KK   9      // 3x3
#define HO   96
#define WO   96
#define PTOT (NN*HO*WO)          // 73728
#define BM   32                  // positions per block (round-12: halved)
#define KTOT (CIN*KK)            // 1152
#define KSTEPS (KTOT/32)         // 36

typedef _Float16 f16x8 __attribute__((ext_vector_type(8)));
typedef float f32x4  __attribute__((ext_vector_type(4)));

// ---------------------------------------------------------------------------
// helpers
// ---------------------------------------------------------------------------
__device__ __forceinline__ __half2 u2h2(unsigned u) {
    union { unsigned u; __half2 h; } c; c.u = u; return c.h;
}
__device__ __forceinline__ unsigned h22u(__half2 h) {
    union { unsigned u; __half2 h; } c; c.h = h; return c.u;
}
__device__ __forceinline__ unsigned pack_h2(float a, float b) {
    auto v = __builtin_amdgcn_cvt_pkrtz(a, b);        // v_cvt_pkrtz_f16_f32
    union { decltype(v) h; unsigned u; } c; c.h = v; return c.u;
}

// ---------------------------------------------------------------------------
// Preprocess 1: input fp32 NCHW -> fp16 NHWC  (one block per (n,y) plane)
// ---------------------------------------------------------------------------
__global__ __launch_bounds__(256) void to_nhwc_f16(const float* __restrict__ in,
                                                   unsigned short* __restrict__ outp) {
    __shared__ float tile[CIN * 97];
    const int ny = blockIdx.x;                // n*96 + y
    const int n = ny / HH, y = ny - n * HH;
    const float* src = in + (size_t)n * CIN * HH * WW + (size_t)y * WW;
    for (int i = threadIdx.x; i < CIN * WW; i += 256) {
        int c = i / WW, x = i - c * WW;
        tile[c * 97 + x] = src[(size_t)c * HH * WW + x];
    }
    __syncthreads();
    unsigned* dst = (unsigned*)(outp + (size_t)ny * WW * CIN);
    for (int i = threadIdx.x; i < (WW * CIN) / 2; i += 256) {
        int c2 = (i & 63) * 2;
        int x  = i >> 6;
        dst[x * (CIN / 2) + (c2 >> 1)] = pack_h2(tile[c2 * 97 + x], tile[(c2 + 1) * 97 + x]);
    }
}

// ---------------------------------------------------------------------------
// Preprocess 2: weight fp32 [Cout][Cin][9] -> fp16 fragment-packed
// ---------------------------------------------------------------------------
__global__ __launch_bounds__(256) void w_pack(const float* __restrict__ w,
                                              unsigned short* __restrict__ wp) {
    int idx = blockIdx.x * 256 + threadIdx.x;
    if (idx >= KSTEPS * 16 * 64 * 8) return;
    int j  = idx & 7;
    int l  = (idx >> 3) & 63;
    int cb = (idx >> 9) & 15;
    int ks = idx >> 13;
    int co  = cb * 16 + (l & 15);
    int kg  = ks * 32 + ((l >> 4) * 8) + j;
    int tap = kg >> 7;
    int cin = kg & 127;
    _Float16 h = (_Float16)w[((size_t)co * CIN + cin) * KK + tap];
    wp[idx] = *(unsigned short*)&h;
}

// ---------------------------------------------------------------------------
// Main: implicit GEMM, 256 thr / 4 waves; wave = M32 x N64 (acc[2][4]=32).
// Round-11 pipeline (fp16 blend, widened swizzle, 0 bank conflicts) with the
// block halved: LDS 20.5KB -> 7-8 blocks/CU (28+ waves, was 3 blocks/24);
// grid 2304 = exactly 9 blocks/CU (no quantization tail; was 4.5 -> ceil 5).
// NO cross-cluster register pipelining (rounds 4/7/9: spill => WRITE_SIZE
// explosion). Spill tripwire: WRITE >> 90MB => revert.
// LDS: geom [0,3456) | buf0 [3456,11648) | buf1 [11648,19840)
// Epilogue reuses [0,20480) as per-wave transpose tiles (5120 B x 4 waves).
// XCD-chunked blockIdx swizzle: each XCD owns one batch image (L2-resident).
// ---------------------------------------------------------------------------
#define LDS_BYTES  20480
#define BUF0 3456
#define BUF1 11648

__global__ __launch_bounds__(256, 7) void deform_mfma(
    const unsigned short* __restrict__ imgB,   // fp16 NHWC
    const float*          __restrict__ off,    // [N][18][96][96]
    const unsigned short* __restrict__ wPack,  // fp16 frag-packed
    float*                __restrict__ out)    // [N][256][96][96]
{
    __shared__ __align__(16) char smem[LDS_BYTES];
    unsigned* gOff = (unsigned*)smem;                 // [288]
    unsigned* gW0  = (unsigned*)(smem + 1152);        // [288] (w00,w01) fp16
    unsigned* gW1  = (unsigned*)(smem + 2304);        // [288] (w10,w11) fp16

    const int t    = threadIdx.x;                     // 0..255
    const int lane = t & 63;
    const int wv   = t >> 6;                          // 0..3

    // XCD-chunked swizzle (bijective: 2304 % 8 == 0). XCD i -> blocks
    // [i*288,(i+1)*288) = exactly batch n=i (288 blocks per image).
    const int bid  = ((blockIdx.x & 7) * ((PTOT / BM) >> 3)) + (blockIdx.x >> 3);

    const int p0   = bid * BM;
    const int nb   = p0 / (HO * WO);
    const int p0rem = p0 - nb * (HO * WO);

    // ---- one-time geometry precompute for all (tap,pos) : 288 entries ----
    for (int i = t; i < KK * BM; i += 256) {
        int tap = i >> 5, m = i & 31;
        int plin = p0rem + m;
        int ho = plin / WO, wo = plin - ho * WO;
        int kh = tap / 3, kw = tap - kh * 3;
        const float* ob = off + ((size_t)nb * 2 * KK + 2 * tap) * (HO * WO) + plin;
        float py = (float)(ho - 1 + kh) + ob[0];
        float px = (float)(wo - 1 + kw) + ob[HO * WO];
        float y0f = floorf(py), x0f = floorf(px);
        float ly = py - y0f, lx = px - x0f;
        int y0 = (int)y0f, x0 = (int)x0f;

        bool vy0 = (unsigned)y0 < (unsigned)HH;
        bool vy1 = (unsigned)(y0 + 1) < (unsigned)HH;
        bool vx0 = (unsigned)x0 < (unsigned)WW;
        bool vx1 = (unsigned)(x0 + 1) < (unsigned)WW;
        int yc0 = min(max(y0, 0), HH - 1);
        int yc1 = min(max(y0 + 1, 0), HH - 1);
        int xc0 = min(max(x0, 0), WW - 1);
        int xc1 = min(max(x0 + 1, 0), WW - 1);

        float w11 = ly * lx;
        float w10 = ly - w11;
        float w01 = lx - w11;
        float w00 = 1.f - ly - lx + w11;
        w00 = (vy0 && vx0) ? w00 : 0.f;
        w01 = (vy0 && vx1) ? w01 : 0.f;
        w10 = (vy1 && vx0) ? w10 : 0.f;
        w11 = (vy1 && vx1) ? w11 : 0.f;

        unsigned byte00 = (unsigned)(yc0 * WW + xc0) * (CIN * 2);   // < 2^22
        unsigned xs = (xc1 != xc0) ? 1u : 0u;
        unsigned ys = (yc1 != yc0) ? 1u : 0u;
        gOff[i] = byte00 | (xs << 22) | (ys << 23);
        gW0[i]  = pack_h2(w00, w01);
        gW1[i]  = pack_h2(w10, w11);
    }

    f32x4 acc[2][4];
#pragma unroll
    for (int mf = 0; mf < 2; ++mf)
#pragma unroll
        for (int nf = 0; nf < 4; ++nf) acc[mf][nf] = (f32x4)0.f;

    const char* imgN = (const char*)(imgB + (size_t)nb * (HH * WW) * CIN);

    // gather of samp[32 pos][128 cin] for one tap (geometry from LDS);
    // blend entirely in packed fp16 (v_pk_fma_f16 on loaded pairs).
    auto gather = [&](int tap, char* bufw) {
#pragma unroll
        for (int it = 0; it < 2; ++it) {
            int item  = t + it * 256;        // 0..511
            int pos   = item >> 4;           // 0..31
            int chunk = item & 15;           // 8-cin chunk
            int gi    = tap * 32 + pos;

            unsigned ofl  = gOff[gi];
            unsigned w0pk = gW0[gi];
            unsigned w1pk = gW1[gi];

            unsigned a00 = (ofl & 0x3fffffu) + (unsigned)(chunk * 16);
            unsigned dx  = (ofl >> 14) & 0x100u;            // xs*256
            unsigned dy  = ((ofl >> 23) & 1u) * 24576u;     // ys*96*256

            uint4 r00 = *(const uint4*)(imgN + a00);
            uint4 r01 = *(const uint4*)(imgN + a00 + dx);
            uint4 r10 = *(const uint4*)(imgN + a00 + dy);
            uint4 r11 = *(const uint4*)(imgN + a00 + dy + dx);

            // splat packed fp16 weights
            unsigned u00 = w0pk & 0xffffu;      u00 |= u00 << 16;
            unsigned u01 = w0pk >> 16;          u01 |= u01 << 16;
            unsigned u10 = w1pk & 0xffffu;      u10 |= u10 << 16;
            unsigned u11 = w1pk >> 16;          u11 |= u11 << 16;
            __half2 w00s = u2h2(u00), w01s = u2h2(u01);
            __half2 w10s = u2h2(u10), w11s = u2h2(u11);

            unsigned pk[4];
            __half2 s;
            s = __hmul2(u2h2(r11.x), w11s);
            s = __hfma2(u2h2(r10.x), w10s, s);
            s = __hfma2(u2h2(r01.x), w01s, s);
            s = __hfma2(u2h2(r00.x), w00s, s);
            pk[0] = h22u(s);
            s = __hmul2(u2h2(r11.y), w11s);
            s = __hfma2(u2h2(r10.y), w10s, s);
            s = __hfma2(u2h2(r01.y), w01s, s);
            s = __hfma2(u2h2(r00.y), w00s, s);
            pk[1] = h22u(s);
            s = __hmul2(u2h2(r11.z), w11s);
            s = __hfma2(u2h2(r10.z), w10s, s);
            s = __hfma2(u2h2(r01.z), w01s, s);
            s = __hfma2(u2h2(r00.z), w00s, s);
            pk[2] = h22u(s);
            s = __hmul2(u2h2(r11.w), w11s);
            s = __hfma2(u2h2(r10.w), w10s, s);
            s = __hfma2(u2h2(r01.w), w01s, s);
            s = __hfma2(u2h2(r00.w), w00s, s);
            pk[3] = h22u(s);

            int byte = pos * 256 + chunk * 16;
            byte ^= (pos & 15) << 4;                      // widened swizzle
            *(uint4*)(bufw + byte) = make_uint4(pk[0], pk[1], pk[2], pk[3]);
        }
    };

    __syncthreads();                 // geom visible
    gather(0, smem + BUF0);

    for (int tap = 0; tap < KK; ++tap) {
        __syncthreads();             // buf[tap&1] fully written
        const char* bufr = smem + ((tap & 1) ? BUF1 : BUF0);

        // ---- 4 K-steps of MFMA on buf[tap&1] ----
#pragma unroll
        for (int cs = 0; cs < 4; ++cs) {
            int ks = tap * 4 + cs;
            f16x8 a[2], b[4];
#pragma unroll
            for (int mf = 0; mf < 2; ++mf) {
                int row  = mf * 16 + (lane & 15);
                int byte = row * 256 + cs * 64 + ((lane >> 4) * 16);
                byte ^= (row & 15) << 4;                  // widened swizzle
                a[mf] = *(const f16x8*)(bufr + byte);
            }
#pragma unroll
            for (int nf = 0; nf < 4; ++nf) {
                int tile = ks * 16 + (wv * 4 + nf);
                b[nf] = *(const f16x8*)(wPack + (size_t)tile * 512 + lane * 8);
            }
            __builtin_amdgcn_s_setprio(1);
#pragma unroll
            for (int mf = 0; mf < 2; ++mf)
#pragma unroll
                for (int nf = 0; nf < 4; ++nf)
                    acc[mf][nf] = __builtin_amdgcn_mfma_f32_16x16x32_f16(
                        a[mf], b[nf], acc[mf][nf], 0, 0, 0);
            __builtin_amdgcn_s_setprio(0);
        }

        // ---- overlap: gather next tap into the other buffer ----
        if (tap + 1 < KK) gather(tap + 1, smem + ((tap & 1) ? BUF0 : BUF1));
    }

    // ---- epilogue: per-wave, per-mf LDS transpose -> coalesced row writes ----
    __syncthreads();
    float* cT = (float*)smem + wv * (64 * 20);            // 5120 B per wave
    const int colbase = lane & 15;
    const int rowq    = lane >> 4;                        // 0..3
    float* outbase = out + ((size_t)nb * COUT + wv * 64 + lane) * (HO * WO) + p0rem;
#pragma unroll
    for (int mf = 0; mf < 2; ++mf) {
#pragma unroll
        for (int nf = 0; nf < 4; ++nf) {
            int co = nf * 16 + colbase;
            *(f32x4*)&cT[co * 20 + rowq * 4] = acc[mf][nf];
        }
        asm volatile("s_waitcnt lgkmcnt(0)" ::: "memory");
        __builtin_amdgcn_sched_barrier(0);
#pragma unroll
        for (int q = 0; q < 4; ++q) {
            f32x4 v = *(f32x4*)&cT[lane * 20 + q * 4];
            *(float4*)(outbase + mf * 16 + q * 4) = *(float4*)&v;
        }
    }
}

// ---------------------------------------------------------------------------
// Fallback (fp32, no workspace) — correctness insurance if ws is too small.
// ---------------------------------------------------------------------------
__global__ __launch_bounds__(256) void deform_fallback(const float* __restrict__ img,
                                                       const float* __restrict__ off,
                                                       const float* __restrict__ wgt,
                                                       float* __restrict__ out) {
    __shared__ float samp[8][CIN];
    const int tid = threadIdx.x;
    const int p0  = blockIdx.x * 8;
    const int n   = p0 / (HO * WO);
    const int rem = p0 % (HO * WO);
    const int ho  = rem / WO;
    const int wo0 = rem % WO;
    float acc[8];
#pragma unroll
    for (int t = 0; t < 8; ++t) acc[t] = 0.f;
    for (int k = 0; k < KK; ++k) {
        __syncthreads();
        const int kh = k / 3, kw = k % 3;
#pragma unroll
        for (int it = 0; it < 4; ++it) {
            int idx = tid + it * 256;
            int t   = idx >> 7;
            int c   = idx & (CIN - 1);
            int wo  = wo0 + t;
            float dy = off[(((size_t)n * 2 * KK + 2 * k) * HO + ho) * WO + wo];
            float dx = off[(((size_t)n * 2 * KK + 2 * k + 1) * HO + ho) * WO + wo];
            float py = (float)(ho - 1 + kh) + dy;
            float px = (float)(wo - 1 + kw) + dx;
            float y0f = floorf(py), x0f = floorf(px);
            float ly = py - y0f, lx = px - x0f;
            int y0 = (int)y0f, x0 = (int)x0f;
            float v00 = 0.f, v01 = 0.f, v10 = 0.f, v11 = 0.f;
            const float* base = img + ((size_t)n * CIN + c) * HH * WW;
            if ((unsigned)y0 < (unsigned)HH) {
                const float* row = base + (size_t)y0 * WW;
                if ((unsigned)x0 < (unsigned)WW)       v00 = row[x0];
                if ((unsigned)(x0 + 1) < (unsigned)WW) v01 = row[x0 + 1];
            }
            if ((unsigned)(y0 + 1) < (unsigned)HH) {
                const float* row = base + (size_t)(y0 + 1) * WW;
                if ((unsigned)x0 < (unsigned)WW)       v10 = row[x0];
                if ((unsigned)(x0 + 1) < (unsigned)WW) v11 = row[x0 + 1];
            }
            float top = v00 + lx * (v01 - v00);
            float bot = v10 + lx * (v11 - v10);
            samp[t][c] = top + ly * (bot - top);
        }
        __syncthreads();
        const float* wk = wgt + (size_t)tid * CIN * KK + k;
        for (int c = 0; c < CIN; c += 4) {
            float w0 = wk[(c + 0) * KK], w1 = wk[(c + 1) * KK];
            float w2 = wk[(c + 2) * KK], w3 = wk[(c + 3) * KK];
#pragma unroll
            for (int t = 0; t < 8; ++t) {
                const float4 s = *(const float4*)&samp[t][c];
                acc[t] = fmaf(s.x, w0, acc[t]);
                acc[t] = fmaf(s.y, w1, acc[t]);
                acc[t] = fmaf(s.z, w2, acc[t]);
                acc[t] = fmaf(s.w, w3, acc[t]);
            }
        }
    }
#pragma unroll
    for (int t = 0; t < 8; ++t)
        out[(((size_t)n * COUT + tid) * HO + ho) * WO + wo0 + t] = acc[t];
}

extern "C" void kernel_launch(void* const* d_in, const int* in_sizes, int n_in,
                              void* d_out, int out_size, void* d_ws, size_t ws_size,
                              hipStream_t stream) {
    const float* inp = (const float*)d_in[0];
    const float* off = (const float*)d_in[1];
    const float* wgt = (const float*)d_in[2];
    float* out = (float*)d_out;

    const size_t img_bytes = (size_t)NN * HH * WW * CIN * 2;
    const size_t wp_bytes  = (size_t)KSTEPS * 16 * 64 * 8 * 2;

    if (ws_size >= img_bytes + wp_bytes) {
        unsigned short* imgB  = (unsigned short*)d_ws;
        unsigned short* wPack = (unsigned short*)((char*)d_ws + img_bytes);
        to_nhwc_f16<<<NN * HH, 256, 0, stream>>>(inp, imgB);
        w_pack<<<(KSTEPS * 16 * 64 * 8) / 256, 256, 0, stream>>>(wgt, wPack);
        deform_mfma<<<PTOT / BM, 256, 0, stream>>>(imgB, off, wPack, out);
    } else {
        deform_fallback<<<PTOT / 8, 256, 0, stream>>>(inp, off, wgt, out);
    }
}

// Round 13
// 107.441 us; speedup vs baseline: 1.0487x; 1.0487x over previous
//
#include <hip/hip_runtime.h>
#include <hip/hip_bf16.h>
#include <hip/hip_fp16.h>

#define NN   8
#define CIN  128
#define HH   96
#define WW   96
#define COUT 256
#define KK   9      // 3x3
#define HO   96
#define WO   96
#define NPOS (HO*WO)             // 9216
#define PTOT (NN*HO*WO)          // 73728
#define BM   64                  // positions per block
#define KTOT (CIN*KK)            // 1152
#define KSTEPS (KTOT/32)         // 36

typedef _Float16 f16x8 __attribute__((ext_vector_type(8)));
typedef float f32x4  __attribute__((ext_vector_type(4)));

// ---------------------------------------------------------------------------
// helpers
// ---------------------------------------------------------------------------
__device__ __forceinline__ __half2 u2h2(unsigned u) {
    union { unsigned u; __half2 h; } c; c.u = u; return c.h;
}
__device__ __forceinline__ unsigned h22u(__half2 h) {
    union { unsigned u; __half2 h; } c; c.h = h; return c.u;
}
__device__ __forceinline__ unsigned pack_h2(float a, float b) {
    auto v = __builtin_amdgcn_cvt_pkrtz(a, b);        // v_cvt_pkrtz_f16_f32
    union { decltype(v) h; unsigned u; } c; c.h = v; return c.u;
}

// ---------------------------------------------------------------------------
// Preprocess 1: input fp32 NCHW -> fp16 NHWC  (one block per (n,y) plane)
// ---------------------------------------------------------------------------
__global__ __launch_bounds__(256) void to_nhwc_f16(const float* __restrict__ in,
                                                   unsigned short* __restrict__ outp) {
    __shared__ float tile[CIN * 97];
    const int ny = blockIdx.x;                // n*96 + y
    const int n = ny / HH, y = ny - n * HH;
    const float* src = in + (size_t)n * CIN * HH * WW + (size_t)y * WW;
    for (int i = threadIdx.x; i < CIN * WW; i += 256) {
        int c = i / WW, x = i - c * WW;
        tile[c * 97 + x] = src[(size_t)c * HH * WW + x];
    }
    __syncthreads();
    unsigned* dst = (unsigned*)(outp + (size_t)ny * WW * CIN);
    for (int i = threadIdx.x; i < (WW * CIN) / 2; i += 256) {
        int c2 = (i & 63) * 2;
        int x  = i >> 6;
        dst[x * (CIN / 2) + (c2 >> 1)] = pack_h2(tile[c2 * 97 + x], tile[(c2 + 1) * 97 + x]);
    }
}

// ---------------------------------------------------------------------------
// Preprocess 2: weight fp32 [Cout][Cin][9] -> fp16 fragment-packed
// ---------------------------------------------------------------------------
__global__ __launch_bounds__(256) void w_pack(const float* __restrict__ w,
                                              unsigned short* __restrict__ wp) {
    int idx = blockIdx.x * 256 + threadIdx.x;
    if (idx >= KSTEPS * 16 * 64 * 8) return;
    int j  = idx & 7;
    int l  = (idx >> 3) & 63;
    int cb = (idx >> 9) & 15;
    int ks = idx >> 13;
    int co  = cb * 16 + (l & 15);
    int kg  = ks * 32 + ((l >> 4) * 8) + j;
    int tap = kg >> 7;
    int cin = kg & 127;
    _Float16 h = (_Float16)w[((size_t)co * CIN + cin) * KK + tap];
    wp[idx] = *(unsigned short*)&h;
}

// ---------------------------------------------------------------------------
// Preprocess 3: bilinear geometry table, one uint4 per (n, tap, pos):
//   .x = byte00 | xs<<22 | ys<<23   .y = (w00,w01) fp16   .z = (w10,w11) fp16
// Moves the per-block geometry VALU phase out of the hot kernel and frees
// 6.9KB LDS there (39.7KB -> 32KB exactly -> robust 4 blocks/CU).
// ---------------------------------------------------------------------------
__global__ __launch_bounds__(256) void geom_pack(const float* __restrict__ off,
                                                 uint4* __restrict__ gws) {
    int idx = blockIdx.x * 256 + threadIdx.x;      // < NN*KK*NPOS = 663552
    if (idx >= NN * KK * NPOS) return;
    int plin = idx % NPOS;
    int r    = idx / NPOS;
    int tap  = r % KK;
    int n    = r / KK;
    int ho = plin / WO, wo = plin - ho * WO;
    int kh = tap / 3, kw = tap - kh * 3;
    const float* ob = off + ((size_t)n * 2 * KK + 2 * tap) * NPOS + plin;
    float py = (float)(ho - 1 + kh) + ob[0];
    float px = (float)(wo - 1 + kw) + ob[NPOS];
    float y0f = floorf(py), x0f = floorf(px);
    float ly = py - y0f, lx = px - x0f;
    int y0 = (int)y0f, x0 = (int)x0f;

    bool vy0 = (unsigned)y0 < (unsigned)HH;
    bool vy1 = (unsigned)(y0 + 1) < (unsigned)HH;
    bool vx0 = (unsigned)x0 < (unsigned)WW;
    bool vx1 = (unsigned)(x0 + 1) < (unsigned)WW;
    int yc0 = min(max(y0, 0), HH - 1);
    int yc1 = min(max(y0 + 1, 0), HH - 1);
    int xc0 = min(max(x0, 0), WW - 1);
    int xc1 = min(max(x0 + 1, 0), WW - 1);

    float w11 = ly * lx;
    float w10 = ly - w11;
    float w01 = lx - w11;
    float w00 = 1.f - ly - lx + w11;
    w00 = (vy0 && vx0) ? w00 : 0.f;
    w01 = (vy0 && vx1) ? w01 : 0.f;
    w10 = (vy1 && vx0) ? w10 : 0.f;
    w11 = (vy1 && vx1) ? w11 : 0.f;

    unsigned byte00 = (unsigned)(yc0 * WW + xc0) * (CIN * 2);   // < 2^22
    unsigned xs = (xc1 != xc0) ? 1u : 0u;
    unsigned ys = (yc1 != yc0) ? 1u : 0u;
    gws[idx] = make_uint4(byte00 | (xs << 22) | (ys << 23),
                          pack_h2(w00, w01), pack_h2(w10, w11), 0u);
}

// ---------------------------------------------------------------------------
// Main: implicit GEMM, 512 thr / 8 waves; wave = M64 x N32 (acc[4][2]=32).
// Round-11 structure/pipeline (fp16 packed blend, widened swizzle, 0 bank
// conflicts, proven 86.7us) with geometry read from the global table:
// LDS = exactly 32KB (two 16KB samp buffers) -> 4 blocks/CU; gather's geom
// access = one coalesced global_load_dwordx4 (L2-resident, 10.6MB table).
// NO cross-cluster register pipelining (rounds 4/7/9: spill => WRITE_SIZE
// explosion). Spill tripwire: WRITE >> 90MB => revert.
// XCD-chunked blockIdx swizzle: each XCD owns one batch image (L2-resident).
// ---------------------------------------------------------------------------
#define LDS_BYTES  32768
#define BUF0 0
#define BUF1 16384

__global__ __launch_bounds__(512, 6) void deform_mfma(
    const unsigned short* __restrict__ imgB,   // fp16 NHWC
    const uint4*          __restrict__ geomW,  // geometry table
    const unsigned short* __restrict__ wPack,  // fp16 frag-packed
    float*                __restrict__ out)    // [N][256][96][96]
{
    __shared__ __align__(16) char smem[LDS_BYTES];

    const int t    = threadIdx.x;                     // 0..511
    const int lane = t & 63;
    const int wv   = t >> 6;                          // 0..7

    // XCD-chunked swizzle (bijective: 1152 % 8 == 0).
    const int bid  = ((blockIdx.x & 7) * ((PTOT / BM) >> 3)) + (blockIdx.x >> 3);

    const int p0   = bid * BM;
    const int nb   = p0 / NPOS;
    const int p0rem = p0 - nb * NPOS;

    f32x4 acc[4][2];
#pragma unroll
    for (int mf = 0; mf < 4; ++mf)
#pragma unroll
        for (int nf = 0; nf < 2; ++nf) acc[mf][nf] = (f32x4)0.f;

    const char* imgN = (const char*)(imgB + (size_t)nb * (HH * WW) * CIN);

    // gather of samp[64 pos][128 cin] for one tap (geometry from global table);
    // blend entirely in packed fp16 (v_pk_fma_f16 on loaded pairs).
    auto gather = [&](int tap, char* bufw) {
        const uint4* gp = geomW + (size_t)(nb * KK + tap) * NPOS + p0rem;
#pragma unroll
        for (int it = 0; it < 2; ++it) {
            int item  = t + it * 512;        // 0..1023
            int pos   = item >> 4;           // 0..63
            int chunk = item & 15;           // 8-cin chunk

            uint4 g = gp[pos];
            unsigned ofl  = g.x;
            unsigned w0pk = g.y;
            unsigned w1pk = g.z;

            unsigned a00 = (ofl & 0x3fffffu) + (unsigned)(chunk * 16);
            unsigned dx  = (ofl >> 14) & 0x100u;            // xs*256
            unsigned dy  = ((ofl >> 23) & 1u) * 24576u;     // ys*96*256

            uint4 r00 = *(const uint4*)(imgN + a00);
            uint4 r01 = *(const uint4*)(imgN + a00 + dx);
            uint4 r10 = *(const uint4*)(imgN + a00 + dy);
            uint4 r11 = *(const uint4*)(imgN + a00 + dy + dx);

            // splat packed fp16 weights
            unsigned u00 = w0pk & 0xffffu;      u00 |= u00 << 16;
            unsigned u01 = w0pk >> 16;          u01 |= u01 << 16;
            unsigned u10 = w1pk & 0xffffu;      u10 |= u10 << 16;
            unsigned u11 = w1pk >> 16;          u11 |= u11 << 16;
            __half2 w00s = u2h2(u00), w01s = u2h2(u01);
            __half2 w10s = u2h2(u10), w11s = u2h2(u11);

            unsigned pk[4];
            __half2 s;
            s = __hmul2(u2h2(r11.x), w11s);
            s = __hfma2(u2h2(r10.x), w10s, s);
            s = __hfma2(u2h2(r01.x), w01s, s);
            s = __hfma2(u2h2(r00.x), w00s, s);
            pk[0] = h22u(s);
            s = __hmul2(u2h2(r11.y), w11s);
            s = __hfma2(u2h2(r10.y), w10s, s);
            s = __hfma2(u2h2(r01.y), w01s, s);
            s = __hfma2(u2h2(r00.y), w00s, s);
            pk[1] = h22u(s);
            s = __hmul2(u2h2(r11.z), w11s);
            s = __hfma2(u2h2(r10.z), w10s, s);
            s = __hfma2(u2h2(r01.z), w01s, s);
            s = __hfma2(u2h2(r00.z), w00s, s);
            pk[2] = h22u(s);
            s = __hmul2(u2h2(r11.w), w11s);
            s = __hfma2(u2h2(r10.w), w10s, s);
            s = __hfma2(u2h2(r01.w), w01s, s);
            s = __hfma2(u2h2(r00.w), w00s, s);
            pk[3] = h22u(s);

            int byte = pos * 256 + chunk * 16;
            byte ^= (pos & 15) << 4;                      // widened swizzle
            *(uint4*)(bufw + byte) = make_uint4(pk[0], pk[1], pk[2], pk[3]);
        }
    };

    gather(0, smem + BUF0);

    for (int tap = 0; tap < KK; ++tap) {
        __syncthreads();             // buf[tap&1] fully written
        const char* bufr = smem + ((tap & 1) ? BUF1 : BUF0);

        // ---- 4 K-steps of MFMA on buf[tap&1] ----
#pragma unroll
        for (int cs = 0; cs < 4; ++cs) {
            int ks = tap * 4 + cs;
            f16x8 a[4], b[2];
#pragma unroll
            for (int mf = 0; mf < 4; ++mf) {
                int row  = mf * 16 + (lane & 15);
                int byte = row * 256 + cs * 64 + ((lane >> 4) * 16);
                byte ^= (row & 15) << 4;                  // widened swizzle
                a[mf] = *(const f16x8*)(bufr + byte);
            }
#pragma unroll
            for (int nf = 0; nf < 2; ++nf) {
                int tile = ks * 16 + (wv * 2 + nf);
                b[nf] = *(const f16x8*)(wPack + (size_t)tile * 512 + lane * 8);
            }
            __builtin_amdgcn_s_setprio(1);
#pragma unroll
            for (int mf = 0; mf < 4; ++mf)
#pragma unroll
                for (int nf = 0; nf < 2; ++nf)
                    acc[mf][nf] = __builtin_amdgcn_mfma_f32_16x16x32_f16(
                        a[mf], b[nf], acc[mf][nf], 0, 0, 0);
            __builtin_amdgcn_s_setprio(0);
        }

        // ---- overlap: gather next tap into the other buffer ----
        if (tap + 1 < KK) gather(tap + 1, smem + ((tap & 1) ? BUF0 : BUF1));
    }

    // ---- epilogue: per-wave, per-mf LDS transpose -> coalesced row writes ----
    __syncthreads();
    float* cT = (float*)smem + wv * (32 * 20);            // 2560 B per wave
    const int colbase = lane & 15;
    const int rowq    = lane >> 4;                        // 0..3
    const int co2     = lane & 31;
    const int half    = lane >> 5;                        // 0..1
    float* outbase = out + ((size_t)nb * COUT + wv * 32 + co2) * (HO * WO) + p0rem;
#pragma unroll
    for (int mf = 0; mf < 4; ++mf) {
#pragma unroll
        for (int nf = 0; nf < 2; ++nf) {
            int co = nf * 16 + colbase;
            *(f32x4*)&cT[co * 20 + rowq * 4] = acc[mf][nf];
        }
        asm volatile("s_waitcnt lgkmcnt(0)" ::: "memory");
        __builtin_amdgcn_sched_barrier(0);
        f32x4 v0 = *(f32x4*)&cT[co2 * 20 + half * 8];
        f32x4 v1 = *(f32x4*)&cT[co2 * 20 + half * 8 + 4];
        *(float4*)(outbase + mf * 16 + half * 8)     = *(float4*)&v0;
        *(float4*)(outbase + mf * 16 + half * 8 + 4) = *(float4*)&v1;
    }
}

// ---------------------------------------------------------------------------
// Fallback (fp32, no workspace) — correctness insurance if ws is too small.
// ---------------------------------------------------------------------------
__global__ __launch_bounds__(256) void deform_fallback(const float* __restrict__ img,
                                                       const float* __restrict__ off,
                                                       const float* __restrict__ wgt,
                                                       float* __restrict__ out) {
    __shared__ float samp[8][CIN];
    const int tid = threadIdx.x;
    const int p0  = blockIdx.x * 8;
    const int n   = p0 / (HO * WO);
    const int rem = p0 % (HO * WO);
    const int ho  = rem / WO;
    const int wo0 = rem % WO;
    float acc[8];
#pragma unroll
    for (int t = 0; t < 8; ++t) acc[t] = 0.f;
    for (int k = 0; k < KK; ++k) {
        __syncthreads();
        const int kh = k / 3, kw = k % 3;
#pragma unroll
        for (int it = 0; it < 4; ++it) {
            int idx = tid + it * 256;
            int t   = idx >> 7;
            int c   = idx & (CIN - 1);
            int wo  = wo0 + t;
            float dy = off[(((size_t)n * 2 * KK + 2 * k) * HO + ho) * WO + wo];
            float dx = off[(((size_t)n * 2 * KK + 2 * k + 1) * HO + ho) * WO + wo];
            float py = (float)(ho - 1 + kh) + dy;
            float px = (float)(wo - 1 + kw) + dx;
            float y0f = floorf(py), x0f = floorf(px);
            float ly = py - y0f, lx = px - x0f;
            int y0 = (int)y0f, x0 = (int)x0f;
            float v00 = 0.f, v01 = 0.f, v10 = 0.f, v11 = 0.f;
            const float* base = img + ((size_t)n * CIN + c) * HH * WW;
            if ((unsigned)y0 < (unsigned)HH) {
                const float* row = base + (size_t)y0 * WW;
                if ((unsigned)x0 < (unsigned)WW)       v00 = row[x0];
                if ((unsigned)(x0 + 1) < (unsigned)WW) v01 = row[x0 + 1];
            }
            if ((unsigned)(y0 + 1) < (unsigned)HH) {
                const float* row = base + (size_t)(y0 + 1) * WW;
                if ((unsigned)x0 < (unsigned)WW)       v10 = row[x0];
                if ((unsigned)(x0 + 1) < (unsigned)WW) v11 = row[x0 + 1];
            }
            float top = v00 + lx * (v01 - v00);
            float bot = v10 + lx * (v11 - v10);
            samp[t][c] = top + ly * (bot - top);
        }
        __syncthreads();
        const float* wk = wgt + (size_t)tid * CIN * KK + k;
        for (int c = 0; c < CIN; c += 4) {
            float w0 = wk[(c + 0) * KK], w1 = wk[(c + 1) * KK];
            float w2 = wk[(c + 2) * KK], w3 = wk[(c + 3) * KK];
#pragma unroll
            for (int t = 0; t < 8; ++t) {
                const float4 s = *(const float4*)&samp[t][c];
                acc[t] = fmaf(s.x, w0, acc[t]);
                acc[t] = fmaf(s.y, w1, acc[t]);
                acc[t] = fmaf(s.z, w2, acc[t]);
                acc[t] = fmaf(s.w, w3, acc[t]);
            }
        }
    }
#pragma unroll
    for (int t = 0; t < 8; ++t)
        out[(((size_t)n * COUT + tid) * HO + ho) * WO + wo0 + t] = acc[t];
}

extern "C" void kernel_launch(void* const* d_in, const int* in_sizes, int n_in,
                              void* d_out, int out_size, void* d_ws, size_t ws_size,
                              hipStream_t stream) {
    const float* inp = (const float*)d_in[0];
    const float* off = (const float*)d_in[1];
    const float* wgt = (const float*)d_in[2];
    float* out = (float*)d_out;

    const size_t img_bytes  = (size_t)NN * HH * WW * CIN * 2;        // 18,874,368
    const size_t wp_bytes   = (size_t)KSTEPS * 16 * 64 * 8 * 2;      //    589,824
    const size_t geom_bytes = (size_t)NN * KK * NPOS * 16;           // 10,616,832

    if (ws_size >= img_bytes + wp_bytes + geom_bytes) {
        unsigned short* imgB  = (unsigned short*)d_ws;
        unsigned short* wPack = (unsigned short*)((char*)d_ws + img_bytes);
        uint4*          geomW = (uint4*)((char*)d_ws + img_bytes + wp_bytes);
        to_nhwc_f16<<<NN * HH, 256, 0, stream>>>(inp, imgB);
        w_pack<<<(KSTEPS * 16 * 64 * 8) / 256, 256, 0, stream>>>(wgt, wPack);
        geom_pack<<<(NN * KK * NPOS + 255) / 256, 256, 0, stream>>>(off, geomW);
        deform_mfma<<<PTOT / BM, 512, 0, stream>>>(imgB, geomW, wPack, out);
    } else {
        deform_fallback<<<PTOT / 8, 256, 0, stream>>>(inp, off, wgt, out);
    }
}

// Round 14
// 97.791 us; speedup vs baseline: 1.1522x; 1.0987x over previous
//
#include <hip/hip_runtime.h>
#include <hip/hip_bf16.h>
#include <hip/hip_fp16.h>

#define NN   8
#define CIN  128
#define HH   96
#define WW   96
#define COUT 256
#define KK   9      // 3x3
#define HO   96
#define WO   96
#define PTOT (NN*HO*WO)          // 73728
#define BM   64                  // positions per block
#define KTOT (CIN*KK)            // 1152
#define KSTEPS (KTOT/32)         // 36

typedef _Float16 f16x8 __attribute__((ext_vector_type(8)));
typedef float f32x4  __attribute__((ext_vector_type(4)));

// ---------------------------------------------------------------------------
// helpers
// ---------------------------------------------------------------------------
__device__ __forceinline__ __half2 u2h2(unsigned u) {
    union { unsigned u; __half2 h; } c; c.u = u; return c.h;
}
__device__ __forceinline__ unsigned h22u(__half2 h) {
    union { unsigned u; __half2 h; } c; c.h = h; return c.u;
}
__device__ __forceinline__ unsigned pack_h2(float a, float b) {
    auto v = __builtin_amdgcn_cvt_pkrtz(a, b);        // v_cvt_pkrtz_f16_f32
    union { decltype(v) h; unsigned u; } c; c.h = v; return c.u;
}

// ---------------------------------------------------------------------------
// Preprocess 1: input fp32 NCHW -> fp16 NHWC  (one block per (n,y) plane)
// ---------------------------------------------------------------------------
__global__ __launch_bounds__(256) void to_nhwc_f16(const float* __restrict__ in,
                                                   unsigned short* __restrict__ outp) {
    __shared__ float tile[CIN * 97];
    const int ny = blockIdx.x;                // n*96 + y
    const int n = ny / HH, y = ny - n * HH;
    const float* src = in + (size_t)n * CIN * HH * WW + (size_t)y * WW;
    for (int i = threadIdx.x; i < CIN * WW; i += 256) {
        int c = i / WW, x = i - c * WW;
        tile[c * 97 + x] = src[(size_t)c * HH * WW + x];
    }
    __syncthreads();
    unsigned* dst = (unsigned*)(outp + (size_t)ny * WW * CIN);
    for (int i = threadIdx.x; i < (WW * CIN) / 2; i += 256) {
        int c2 = (i & 63) * 2;
        int x  = i >> 6;
        dst[x * (CIN / 2) + (c2 >> 1)] = pack_h2(tile[c2 * 97 + x], tile[(c2 + 1) * 97 + x]);
    }
}

// ---------------------------------------------------------------------------
// Preprocess 2: weight fp32 [Cout][Cin][9] -> fp16 fragment-packed
// ---------------------------------------------------------------------------
__global__ __launch_bounds__(256) void w_pack(const float* __restrict__ w,
                                              unsigned short* __restrict__ wp) {
    int idx = blockIdx.x * 256 + threadIdx.x;
    if (idx >= KSTEPS * 16 * 64 * 8) return;
    int j  = idx & 7;
    int l  = (idx >> 3) & 63;
    int cb = (idx >> 9) & 15;
    int ks = idx >> 13;
    int co  = cb * 16 + (l & 15);
    int kg  = ks * 32 + ((l >> 4) * 8) + j;
    int tap = kg >> 7;
    int cin = kg & 127;
    _Float16 h = (_Float16)w[((size_t)co * CIN + cin) * KK + tap];
    wp[idx] = *(unsigned short*)&h;
}

// ---------------------------------------------------------------------------
// Main: implicit GEMM, 512 thr / 8 waves; wave = M64 x N32 (acc[4][2]=32).
// Round-11 structure (86.7us best) + ONE change: gather issues BOTH items'
// 8 corner loads up-front, then blends both — removes one serial L2 latency
// (~300cyc) per tap from the block-critical path. In-flight regs ~44+32acc;
// (512,6)'s 85-cap would spill -> (512,5) (102-cap). LDS unchanged.
// r13 lesson: geometry stays in LDS (global table overflows per-XCD L2).
// Spill tripwire: WRITE >> 90MB => revert to r11 verbatim.
// LDS: geom [0,6912) | buf0 [6912,23296) | buf1 [23296,39680)
// XCD-chunked blockIdx swizzle: each XCD owns one batch image (L2-resident).
// ---------------------------------------------------------------------------
#define GEOM_BYTES 6912
#define LDS_BYTES  39680
#define BUF0 6912
#define BUF1 23296

__global__ __launch_bounds__(512, 5) void deform_mfma(
    const unsigned short* __restrict__ imgB,   // fp16 NHWC
    const float*          __restrict__ off,    // [N][18][96][96]
    const unsigned short* __restrict__ wPack,  // fp16 frag-packed
    float*                __restrict__ out)    // [N][256][96][96]
{
    __shared__ __align__(16) char smem[LDS_BYTES];
    unsigned* gOff = (unsigned*)smem;                 // [576]
    unsigned* gW0  = (unsigned*)(smem + 2304);        // [576] (w00,w01) fp16
    unsigned* gW1  = (unsigned*)(smem + 4608);        // [576] (w10,w11) fp16

    const int t    = threadIdx.x;                     // 0..511
    const int lane = t & 63;
    const int wv   = t >> 6;                          // 0..7

    // XCD-chunked swizzle (bijective: 1152 % 8 == 0).
    const int bid  = ((blockIdx.x & 7) * ((PTOT / BM) >> 3)) + (blockIdx.x >> 3);

    const int p0   = bid * BM;
    const int nb   = p0 / (HO * WO);
    const int p0rem = p0 - nb * (HO * WO);

    // ---- one-time geometry precompute for all (tap,pos) ----
    for (int i = t; i < KK * BM; i += 512) {
        int tap = i >> 6, m = i & 63;
        int plin = p0rem + m;
        int ho = plin / WO, wo = plin - ho * WO;
        int kh = tap / 3, kw = tap - kh * 3;
        const float* ob = off + ((size_t)nb * 2 * KK + 2 * tap) * (HO * WO) + plin;
        float py = (float)(ho - 1 + kh) + ob[0];
        float px = (float)(wo - 1 + kw) + ob[HO * WO];
        float y0f = floorf(py), x0f = floorf(px);
        float ly = py - y0f, lx = px - x0f;
        int y0 = (int)y0f, x0 = (int)x0f;

        bool vy0 = (unsigned)y0 < (unsigned)HH;
        bool vy1 = (unsigned)(y0 + 1) < (unsigned)HH;
        bool vx0 = (unsigned)x0 < (unsigned)WW;
        bool vx1 = (unsigned)(x0 + 1) < (unsigned)WW;
        int yc0 = min(max(y0, 0), HH - 1);
        int yc1 = min(max(y0 + 1, 0), HH - 1);
        int xc0 = min(max(x0, 0), WW - 1);
        int xc1 = min(max(x0 + 1, 0), WW - 1);

        float w11 = ly * lx;
        float w10 = ly - w11;
        float w01 = lx - w11;
        float w00 = 1.f - ly - lx + w11;
        w00 = (vy0 && vx0) ? w00 : 0.f;
        w01 = (vy0 && vx1) ? w01 : 0.f;
        w10 = (vy1 && vx0) ? w10 : 0.f;
        w11 = (vy1 && vx1) ? w11 : 0.f;

        unsigned byte00 = (unsigned)(yc0 * WW + xc0) * (CIN * 2);   // < 2^22
        unsigned xs = (xc1 != xc0) ? 1u : 0u;
        unsigned ys = (yc1 != yc0) ? 1u : 0u;
        gOff[i] = byte00 | (xs << 22) | (ys << 23);
        gW0[i]  = pack_h2(w00, w01);
        gW1[i]  = pack_h2(w10, w11);
    }

    f32x4 acc[4][2];
#pragma unroll
    for (int mf = 0; mf < 4; ++mf)
#pragma unroll
        for (int nf = 0; nf < 2; ++nf) acc[mf][nf] = (f32x4)0.f;

    const char* imgN = (const char*)(imgB + (size_t)nb * (HH * WW) * CIN);

    // gather of samp[64 pos][128 cin] for one tap: issue all 8 corner loads
    // for both items first, then blend both (halves serial L2 latency).
    auto gather = [&](int tap, char* bufw) {
        const int chunk = t & 15;            // 8-cin chunk
        const int pos0  = t >> 4;            // 0..31
        const int pos1  = pos0 + 32;         // 32..63
        const int gi0   = tap * 64 + pos0;
        const int gi1   = tap * 64 + pos1;

        unsigned ofl0 = gOff[gi0], ofl1 = gOff[gi1];
        unsigned w0a  = gW0[gi0],  w1a  = gW1[gi0];
        unsigned w0b  = gW0[gi1],  w1b  = gW1[gi1];

        unsigned a00a = (ofl0 & 0x3fffffu) + (unsigned)(chunk * 16);
        unsigned dxa  = (ofl0 >> 14) & 0x100u;
        unsigned dya  = ((ofl0 >> 23) & 1u) * 24576u;
        unsigned a00b = (ofl1 & 0x3fffffu) + (unsigned)(chunk * 16);
        unsigned dxb  = (ofl1 >> 14) & 0x100u;
        unsigned dyb  = ((ofl1 >> 23) & 1u) * 24576u;

        // issue all 8 loads
        uint4 ra00 = *(const uint4*)(imgN + a00a);
        uint4 ra01 = *(const uint4*)(imgN + a00a + dxa);
        uint4 ra10 = *(const uint4*)(imgN + a00a + dya);
        uint4 ra11 = *(const uint4*)(imgN + a00a + dya + dxa);
        uint4 rb00 = *(const uint4*)(imgN + a00b);
        uint4 rb01 = *(const uint4*)(imgN + a00b + dxb);
        uint4 rb10 = *(const uint4*)(imgN + a00b + dyb);
        uint4 rb11 = *(const uint4*)(imgN + a00b + dyb + dxb);

        // blend item 0
        {
            unsigned u00 = w0a & 0xffffu;  u00 |= u00 << 16;
            unsigned u01 = w0a >> 16;      u01 |= u01 << 16;
            unsigned u10 = w1a & 0xffffu;  u10 |= u10 << 16;
            unsigned u11 = w1a >> 16;      u11 |= u11 << 16;
            __half2 w00s = u2h2(u00), w01s = u2h2(u01);
            __half2 w10s = u2h2(u10), w11s = u2h2(u11);
            unsigned pk[4];
            __half2 s;
            s = __hmul2(u2h2(ra11.x), w11s);
            s = __hfma2(u2h2(ra10.x), w10s, s);
            s = __hfma2(u2h2(ra01.x), w01s, s);
            s = __hfma2(u2h2(ra00.x), w00s, s);
            pk[0] = h22u(s);
            s = __hmul2(u2h2(ra11.y), w11s);
            s = __hfma2(u2h2(ra10.y), w10s, s);
            s = __hfma2(u2h2(ra01.y), w01s, s);
            s = __hfma2(u2h2(ra00.y), w00s, s);
            pk[1] = h22u(s);
            s = __hmul2(u2h2(ra11.z), w11s);
            s = __hfma2(u2h2(ra10.z), w10s, s);
            s = __hfma2(u2h2(ra01.z), w01s, s);
            s = __hfma2(u2h2(ra00.z), w00s, s);
            pk[2] = h22u(s);
            s = __hmul2(u2h2(ra11.w), w11s);
            s = __hfma2(u2h2(ra10.w), w10s, s);
            s = __hfma2(u2h2(ra01.w), w01s, s);
            s = __hfma2(u2h2(ra00.w), w00s, s);
            pk[3] = h22u(s);
            int byte = pos0 * 256 + chunk * 16;
            byte ^= (pos0 & 15) << 4;
            *(uint4*)(bufw + byte) = make_uint4(pk[0], pk[1], pk[2], pk[3]);
        }
        // blend item 1
        {
            unsigned u00 = w0b & 0xffffu;  u00 |= u00 << 16;
            unsigned u01 = w0b >> 16;      u01 |= u01 << 16;
            unsigned u10 = w1b & 0xffffu;  u10 |= u10 << 16;
            unsigned u11 = w1b >> 16;      u11 |= u11 << 16;
            __half2 w00s = u2h2(u00), w01s = u2h2(u01);
            __half2 w10s = u2h2(u10), w11s = u2h2(u11);
            unsigned pk[4];
            __half2 s;
            s = __hmul2(u2h2(rb11.x), w11s);
            s = __hfma2(u2h2(rb10.x), w10s, s);
            s = __hfma2(u2h2(rb01.x), w01s, s);
            s = __hfma2(u2h2(rb00.x), w00s, s);
            pk[0] = h22u(s);
            s = __hmul2(u2h2(rb11.y), w11s);
            s = __hfma2(u2h2(rb10.y), w10s, s);
            s = __hfma2(u2h2(rb01.y), w01s, s);
            s = __hfma2(u2h2(rb00.y), w00s, s);
            pk[1] = h22u(s);
            s = __hmul2(u2h2(rb11.z), w11s);
            s = __hfma2(u2h2(rb10.z), w10s, s);
            s = __hfma2(u2h2(rb01.z), w01s, s);
            s = __hfma2(u2h2(rb00.z), w00s, s);
            pk[2] = h22u(s);
            s = __hmul2(u2h2(rb11.w), w11s);
            s = __hfma2(u2h2(rb10.w), w10s, s);
            s = __hfma2(u2h2(rb01.w), w01s, s);
            s = __hfma2(u2h2(rb00.w), w00s, s);
            pk[3] = h22u(s);
            int byte = pos1 * 256 + chunk * 16;
            byte ^= (pos1 & 15) << 4;
            *(uint4*)(bufw + byte) = make_uint4(pk[0], pk[1], pk[2], pk[3]);
        }
    };

    __syncthreads();                 // geom visible
    gather(0, smem + BUF0);

    for (int tap = 0; tap < KK; ++tap) {
        __syncthreads();             // buf[tap&1] fully written
        const char* bufr = smem + ((tap & 1) ? BUF1 : BUF0);

        // ---- 4 K-steps of MFMA on buf[tap&1] ----
#pragma unroll
        for (int cs = 0; cs < 4; ++cs) {
            int ks = tap * 4 + cs;
            f16x8 a[4], b[2];
#pragma unroll
            for (int mf = 0; mf < 4; ++mf) {
                int row  = mf * 16 + (lane & 15);
                int byte = row * 256 + cs * 64 + ((lane >> 4) * 16);
                byte ^= (row & 15) << 4;                  // widened swizzle
                a[mf] = *(const f16x8*)(bufr + byte);
            }
#pragma unroll
            for (int nf = 0; nf < 2; ++nf) {
                int tile = ks * 16 + (wv * 2 + nf);
                b[nf] = *(const f16x8*)(wPack + (size_t)tile * 512 + lane * 8);
            }
            __builtin_amdgcn_s_setprio(1);
#pragma unroll
            for (int mf = 0; mf < 4; ++mf)
#pragma unroll
                for (int nf = 0; nf < 2; ++nf)
                    acc[mf][nf] = __builtin_amdgcn_mfma_f32_16x16x32_f16(
                        a[mf], b[nf], acc[mf][nf], 0, 0, 0);
            __builtin_amdgcn_s_setprio(0);
        }

        // ---- overlap: gather next tap into the other buffer ----
        if (tap + 1 < KK) gather(tap + 1, smem + ((tap & 1) ? BUF0 : BUF1));
    }

    // ---- epilogue: per-wave, per-mf LDS transpose -> coalesced row writes ----
    __syncthreads();
    float* cT = (float*)smem + wv * (32 * 20);            // 2560 B per wave
    const int colbase = lane & 15;
    const int rowq    = lane >> 4;                        // 0..3
    const int co2     = lane & 31;
    const int half    = lane >> 5;                        // 0..1
    float* outbase = out + ((size_t)nb * COUT + wv * 32 + co2) * (HO * WO) + p0rem;
#pragma unroll
    for (int mf = 0; mf < 4; ++mf) {
#pragma unroll
        for (int nf = 0; nf < 2; ++nf) {
            int co = nf * 16 + colbase;
            *(f32x4*)&cT[co * 20 + rowq * 4] = acc[mf][nf];
        }
        asm volatile("s_waitcnt lgkmcnt(0)" ::: "memory");
        __builtin_amdgcn_sched_barrier(0);
        f32x4 v0 = *(f32x4*)&cT[co2 * 20 + half * 8];
        f32x4 v1 = *(f32x4*)&cT[co2 * 20 + half * 8 + 4];
        *(float4*)(outbase + mf * 16 + half * 8)     = *(float4*)&v0;
        *(float4*)(outbase + mf * 16 + half * 8 + 4) = *(float4*)&v1;
    }
}

// ---------------------------------------------------------------------------
// Fallback (fp32, no workspace) — correctness insurance if ws is too small.
// ---------------------------------------------------------------------------
__global__ __launch_bounds__(256) void deform_fallback(const float* __restrict__ img,
                                                       const float* __restrict__ off,
                                                       const float* __restrict__ wgt,
                                                       float* __restrict__ out) {
    __shared__ float samp[8][CIN];
    const int tid = threadIdx.x;
    const int p0  = blockIdx.x * 8;
    const int n   = p0 / (HO * WO);
    const int rem = p0 % (HO * WO);
    const int ho  = rem / WO;
    const int wo0 = rem % WO;
    float acc[8];
#pragma unroll
    for (int t = 0; t < 8; ++t) acc[t] = 0.f;
    for (int k = 0; k < KK; ++k) {
        __syncthreads();
        const int kh = k / 3, kw = k % 3;
#pragma unroll
        for (int it = 0; it < 4; ++it) {
            int idx = tid + it * 256;
            int t   = idx >> 7;
            int c   = idx & (CIN - 1);
            int wo  = wo0 + t;
            float dy = off[(((size_t)n * 2 * KK + 2 * k) * HO + ho) * WO + wo];
            float dx = off[(((size_t)n * 2 * KK + 2 * k + 1) * HO + ho) * WO + wo];
            float py = (float)(ho - 1 + kh) + dy;
            float px = (float)(wo - 1 + kw) + dx;
            float y0f = floorf(py), x0f = floorf(px);
            float ly = py - y0f, lx = px - x0f;
            int y0 = (int)y0f, x0 = (int)x0f;
            float v00 = 0.f, v01 = 0.f, v10 = 0.f, v11 = 0.f;
            const float* base = img + ((size_t)n * CIN + c) * HH * WW;
            if ((unsigned)y0 < (unsigned)HH) {
                const float* row = base + (size_t)y0 * WW;
                if ((unsigned)x0 < (unsigned)WW)       v00 = row[x0];
                if ((unsigned)(x0 + 1) < (unsigned)WW) v01 = row[x0 + 1];
            }
            if ((unsigned)(y0 + 1) < (unsigned)HH) {
                const float* row = base + (size_t)(y0 + 1) * WW;
                if ((unsigned)x0 < (unsigned)WW)       v10 = row[x0];
                if ((unsigned)(x0 + 1) < (unsigned)WW) v11 = row[x0 + 1];
            }
            float top = v00 + lx * (v01 - v00);
            float bot = v10 + lx * (v11 - v10);
            samp[t][c] = top + ly * (bot - top);
        }
        __syncthreads();
        const float* wk = wgt + (size_t)tid * CIN * KK + k;
        for (int c = 0; c < CIN; c += 4) {
            float w0 = wk[(c + 0) * KK], w1 = wk[(c + 1) * KK];
            float w2 = wk[(c + 2) * KK], w3 = wk[(c + 3) * KK];
#pragma unroll
            for (int t = 0; t < 8; ++t) {
                const float4 s = *(const float4*)&samp[t][c];
                acc[t] = fmaf(s.x, w0, acc[t]);
                acc[t] = fmaf(s.y, w1, acc[t]);
                acc[t] = fmaf(s.z, w2, acc[t]);
                acc[t] = fmaf(s.w, w3, acc[t]);
            }
        }
    }
#pragma unroll
    for (int t = 0; t < 8; ++t)
        out[(((size_t)n * COUT + tid) * HO + ho) * WO + wo0 + t] = acc[t];
}

extern "C" void kernel_launch(void* const* d_in, const int* in_sizes, int n_in,
                              void* d_out, int out_size, void* d_ws, size_t ws_size,
                              hipStream_t stream) {
    const float* inp = (const float*)d_in[0];
    const float* off = (const float*)d_in[1];
    const float* wgt = (const float*)d_in[2];
    float* out = (float*)d_out;

    const size_t img_bytes = (size_t)NN * HH * WW * CIN * 2;
    const size_t wp_bytes  = (size_t)KSTEPS * 16 * 64 * 8 * 2;

    if (ws_size >= img_bytes + wp_bytes) {
        unsigned short* imgB  = (unsigned short*)d_ws;
        unsigned short* wPack = (unsigned short*)((char*)d_ws + img_bytes);
        to_nhwc_f16<<<NN * HH, 256, 0, stream>>>(inp, imgB);
        w_pack<<<(KSTEPS * 16 * 64 * 8) / 256, 256, 0, stream>>>(wgt, wPack);
        deform_mfma<<<PTOT / BM, 512, 0, stream>>>(imgB, off, wPack, out);
    } else {
        deform_fallback<<<PTOT / 8, 256, 0, stream>>>(inp, off, wgt, out);
    }
}